// Round 7
// baseline (201.536 us; speedup 1.0000x reference)
//
#include <hip/hip_runtime.h>
#include <stdint.h>

#define CC 256
#define NN 4096   // H*W = 64*64

typedef __attribute__((ext_vector_type(8))) short short8;
typedef __attribute__((ext_vector_type(4))) float floatx4;
typedef __attribute__((ext_vector_type(4))) unsigned int uint4v;

__device__ __forceinline__ unsigned short f2bf(float f) {
    unsigned int u = __builtin_bit_cast(unsigned int, f);
    u = (u + 0x7FFFu + ((u >> 16) & 1u)) >> 16;   // RNE
    return (unsigned short)u;
}

__device__ __forceinline__ floatx4 mfma16(short8 a, short8 b, floatx4 c) {
    return __builtin_amdgcn_mfma_f32_16x16x32_bf16(a, b, c, 0, 0, 0);
}

// ---------------------------------------------------------------------------
// Fragment layouts (16x16x32 bf16; A-frag == B-frag lane map:
//   element(row = 16*tile + (lane&15), k = 32*kk + (lane>>4)*8 + j)):
// xB[b][nt 256][kk 8][lane][j] : row = n (pixel), k = c   (S A- and B-operands)
// xG[b][mt 64][cct 16][kk2 2][lane][j] : row = c, k = m   (G2 A-operand, R6-proven)
// wF[ct 16][kk 8][lane][j]     : row = out-c, k = in-c    (epilogue A, R6-proven)
// ---------------------------------------------------------------------------

// ---------------------------------------------------------------------------
// k_trans: x -> xB + xG (bf16 fragment-ordered) + partial norms psum.
// grid 1024 (b*4cc*64nc) x 256 thr. Tile [64 c][64 n] in LDS.
// Block covers c0..c0+64, n0..n0+64: complete xB chunks (nt: 4, kk: 2) and
// complete xG chunks (cct: 4, kk2: 2, mt = nc).
// ---------------------------------------------------------------------------
__global__ __launch_bounds__(256) void k_trans(const float* __restrict__ x,
                                               unsigned short* __restrict__ xB,
                                               unsigned short* __restrict__ xG,
                                               float* __restrict__ psum) {
    int blk = blockIdx.x;
    int b  = blk >> 8;
    int cc = (blk >> 6) & 3;
    int nc = blk & 63;
    int c0 = cc << 6, n0 = nc << 6;
    __shared__ float tile[64][65];     // [c-local][n-local], +1 pad
    __shared__ float red[4][64];
    int t = threadIdx.x;
    {
        int c   = t >> 2;
        int nn4 = (t & 3) << 4;
        const float* src = x + (size_t)(b * CC + c0 + c) * NN + n0 + nn4;
        #pragma unroll
        for (int j = 0; j < 16; j += 4) {
            floatx4 v = *(const floatx4*)(src + j);
            tile[c][nn4 + j + 0] = v[0];
            tile[c][nn4 + j + 1] = v[1];
            tile[c][nn4 + j + 2] = v[2];
            tile[c][nn4 + j + 3] = v[3];
        }
    }
    __syncthreads();
    int g = t >> 6, lane = t & 63, l15 = lane & 15, q = lane >> 4;
    // xB frags: ntl = g, kkl 0..1 ; element = tile[32kkl+8q+jj][16g+l15]
    #pragma unroll
    for (int kkl = 0; kkl < 2; ++kkl) {
        unsigned int w[4];
        #pragma unroll
        for (int j = 0; j < 4; ++j) {
            unsigned int lo = f2bf(tile[32 * kkl + 8 * q + 2 * j][16 * g + l15]);
            unsigned int hi = f2bf(tile[32 * kkl + 8 * q + 2 * j + 1][16 * g + l15]);
            w[j] = lo | (hi << 16);
        }
        uint4v p = {w[0], w[1], w[2], w[3]};
        *(uint4v*)(xB + ((size_t)(b * 256 + (n0 >> 4) + g) * 8 + (c0 >> 5) + kkl) * 512
                   + lane * 8) = p;
    }
    // xG frags: cctl = g, kk2 0..1 ; element = tile[16g+l15][32kk2+8q+jj]
    #pragma unroll
    for (int kk2 = 0; kk2 < 2; ++kk2) {
        unsigned int w[4];
        #pragma unroll
        for (int j = 0; j < 4; ++j) {
            unsigned int lo = f2bf(tile[16 * g + l15][32 * kk2 + 8 * q + 2 * j]);
            unsigned int hi = f2bf(tile[16 * g + l15][32 * kk2 + 8 * q + 2 * j + 1]);
            w[j] = lo | (hi << 16);
        }
        uint4v p = {w[0], w[1], w[2], w[3]};
        *(uint4v*)(xG + (size_t)(b * 64 + nc) * 16 * 1024
                   + ((size_t)((c0 >> 4) + g)) * 1024 + kk2 * 512 + lane * 8) = p;
    }
    // partial sum of squares (fp32 exact)
    {
        int n  = t & 63;
        int cq = t >> 6;
        float ss = 0.f;
        #pragma unroll
        for (int i = 0; i < 16; ++i) {
            float v = tile[cq * 16 + i][n];
            ss = fmaf(v, v, ss);
        }
        red[cq][n] = ss;
    }
    __syncthreads();
    if (t < 64) {
        float s = red[0][t] + red[1][t] + red[2][t] + red[3][t];
        psum[((size_t)(b * 64 + nc) * 64 + t) * 4 + cc] = s;
    }
}

// ---------------------------------------------------------------------------
// k_invwcast: blocks 0..63 -> invn ; blocks 64..95 -> wF (merged launches)
// ---------------------------------------------------------------------------
__global__ __launch_bounds__(256) void k_invwcast(const float* __restrict__ psum,
                                                  float* __restrict__ invn,
                                                  const float* __restrict__ Wm,
                                                  unsigned short* __restrict__ wF) {
    int bid = blockIdx.x;
    int t = threadIdx.x;
    if (bid < 64) {
        int i = bid * 256 + t;
        floatx4 p = *(const floatx4*)(psum + (size_t)i * 4);
        float ss = (p[0] + p[1]) + (p[2] + p[3]);
        invn[i] = 1.f / fmaxf(sqrtf(ss), 1e-8f);
    } else {
        int idx = (bid - 64) * 256 + t;          // 0..8191
        int f = idx >> 6, lane = idx & 63;
        int ct = f >> 3, kk = f & 7;
        int l15 = lane & 15, q = lane >> 4;
        const float* src = Wm + (size_t)(16 * ct + l15) * CC + 32 * kk + 8 * q;
        floatx4 a = *(const floatx4*)src;
        floatx4 c = *(const floatx4*)(src + 4);
        unsigned int w0 = f2bf(a[0]) | ((unsigned int)f2bf(a[1]) << 16);
        unsigned int w1 = f2bf(a[2]) | ((unsigned int)f2bf(a[3]) << 16);
        unsigned int w2 = f2bf(c[0]) | ((unsigned int)f2bf(c[1]) << 16);
        unsigned int w3 = f2bf(c[2]) | ((unsigned int)f2bf(c[3]) << 16);
        uint4v p = {w0, w1, w2, w3};
        *(uint4v*)(wF + (size_t)f * 512 + lane * 8) = p;
    }
}

// ---------------------------------------------------------------------------
// k_fused v6: out = W*(X*P) + b*colsum(P); NO LDS staging for keys.
// Block = (b, 64 queries), 512 thr (8 waves), grid 256.
// Per key-tile: bq from xB (coalesced L2), S = aq x bq (R6-proven orient),
// P = relu(S*inv)^2 -> pbuf[it&1] (scalar writes + csum, R6-proven),
// ONE lgkm-only barrier, Z += Xg * P (xG coalesced, R6-proven).
// Epilogue (R6 verbatim): shfl colsum, zbuf (dedicated), O = W*Z + b*s.
// ---------------------------------------------------------------------------
__global__ __launch_bounds__(512, 2) void k_fused(
        const unsigned short* __restrict__ xB,    // S frags
        const unsigned short* __restrict__ xG,    // G2 A frags
        const unsigned short* __restrict__ wF,    // W A-frags
        const float* __restrict__ bias,
        const float* __restrict__ invn,           // [B][N]
        float* __restrict__ out) {                // [B][C][N] f32
    int blk = blockIdx.x;            // b*64 + qtile
    int b  = blk >> 6;
    int n0 = (blk & 63) << 6;
    int t  = threadIdx.x;
    int wv = t >> 6, lane = t & 63;
    int l15 = lane & 15, q = lane >> 4;
    int ms = wv & 3;
    int np = wv >> 2;                // nq pair {2np, 2np+1}

    __shared__ unsigned short pbuf[2][64 * 72];   // [parity][nq row][72 m]
    __shared__ unsigned short zbuf[64 * 264];     // dedicated
    __shared__ float spbuf2[4][64];               // colsum partials [ms][nq]

    const unsigned short* xBb = xB + (size_t)b * 256 * 8 * 512;
    const unsigned short* xGb = xG + (size_t)b * 64 * 16 * 1024;
    const float* invb = invn + b * NN;

    // persistent Xq A-frags from xB (coalesced)
    short8 aq[2][8];
    #pragma unroll
    for (int s = 0; s < 2; ++s)
        #pragma unroll
        for (int kk = 0; kk < 8; ++kk)
            aq[s][kk] = *(const short8*)(xBb
                + ((size_t)((n0 >> 4) + 2 * np + s) * 8 + kk) * 512 + lane * 8);
    float invq[2][4];
    #pragma unroll
    for (int s = 0; s < 2; ++s)
        #pragma unroll
        for (int i = 0; i < 4; ++i)
            invq[s][i] = invb[n0 + 16 * (2 * np + s) + q * 4 + i];

    floatx4 zero4 = {0.f, 0.f, 0.f, 0.f};
    floatx4 Zacc[2][4];              // [ci: cct=wv+8ci][nqs]
    #pragma unroll
    for (int ci = 0; ci < 2; ++ci)
        #pragma unroll
        for (int nqs = 0; nqs < 4; ++nqs) Zacc[ci][nqs] = zero4;
    float csum[2][4];
    #pragma unroll
    for (int s = 0; s < 2; ++s)
        #pragma unroll
        for (int i = 0; i < 4; ++i) csum[s][i] = 0.f;

    for (int it = 0; it < 64; ++it) {
        unsigned short* pb = pbuf[it & 1];
        int m0 = it << 6;
        // ---- coalesced global loads: key B-frags + xG A-frags ----
        short8 bq[8];
        #pragma unroll
        for (int kk = 0; kk < 8; ++kk)
            bq[kk] = *(const short8*)(xBb
                + ((size_t)(it * 4 + ms) * 8 + kk) * 512 + lane * 8);
        short8 xg[2][2];             // [ci][kk2]
        #pragma unroll
        for (int ci = 0; ci < 2; ++ci)
            #pragma unroll
            for (int kk2 = 0; kk2 < 2; ++kk2)
                xg[ci][kk2] = *(const short8*)(xGb
                    + (size_t)(it * 16 + wv + 8 * ci) * 1024 + kk2 * 512 + lane * 8);
        float invm = invb[m0 + 16 * ms + l15];    // S D-col m = 16ms + l15

        // ---- S = Xq^T Xm (R6-proven orientation), parity-split chains ----
        floatx4 s0a = zero4, s0b = zero4, s1a = zero4, s1b = zero4;
        #pragma unroll
        for (int kk = 0; kk < 8; kk += 2) {
            s0a = mfma16(aq[0][kk],     bq[kk],     s0a);
            s1a = mfma16(aq[1][kk],     bq[kk],     s1a);
            s0b = mfma16(aq[0][kk + 1], bq[kk + 1], s0b);
            s1b = mfma16(aq[1][kk + 1], bq[kk + 1], s1b);
        }
        // ---- P = relu(S*inv)^2 -> pb (scalar writes) + csum ----
        #pragma unroll
        for (int s = 0; s < 2; ++s) {
            floatx4 sv = (s == 0) ? (s0a + s0b) : (s1a + s1b);
            unsigned short* pw = pb + (16 * (2 * np + s)) * 72 + 16 * ms + l15;
            #pragma unroll
            for (int i = 0; i < 4; ++i) {
                float v = sv[i] * (invq[s][i] * invm);
                v = fmaxf(v, 0.f);
                v = v * v;
                csum[s][i] += v;
                pw[(q * 4 + i) * 72] = f2bf(v);
            }
        }
        // single barrier: LDS drain only; global loads never drained here
        asm volatile("s_waitcnt lgkmcnt(0)\n\ts_barrier" ::: "memory");

        // ---- Z[c][nq] += Xg * P ----
        #pragma unroll
        for (int kk2 = 0; kk2 < 2; ++kk2)
            #pragma unroll
            for (int nqs = 0; nqs < 4; ++nqs) {
                short8 pbf = *(const short8*)(pb + (16 * nqs + l15) * 72
                                              + kk2 * 32 + q * 8);
                Zacc[0][nqs] = mfma16(xg[0][kk2], pbf, Zacc[0][nqs]);
                Zacc[1][nqs] = mfma16(xg[1][kk2], pbf, Zacc[1][nqs]);
            }
    }

    // ---- colsum reduce over l15 (16-lane groups; pure f32) ----
    #pragma unroll
    for (int mask = 1; mask < 16; mask <<= 1)
        #pragma unroll
        for (int s = 0; s < 2; ++s)
            #pragma unroll
            for (int i = 0; i < 4; ++i)
                csum[s][i] += __shfl_xor(csum[s][i], mask, 64);

    __syncthreads();
    // Z -> zbuf (scalar stores, dedicated LDS)
    #pragma unroll
    for (int ci = 0; ci < 2; ++ci) {
        int cct = wv + 8 * ci;
        #pragma unroll
        for (int nqs = 0; nqs < 4; ++nqs)
            #pragma unroll
            for (int i = 0; i < 4; ++i)
                zbuf[(16 * nqs + l15) * 264 + 16 * cct + 4 * q + i] = f2bf(Zacc[ci][nqs][i]);
    }
    if (l15 == 0) {
        #pragma unroll
        for (int s = 0; s < 2; ++s)
            #pragma unroll
            for (int i = 0; i < 4; ++i)
                spbuf2[ms][16 * (2 * np + s) + 4 * q + i] = csum[s][i];
    }
    __syncthreads();

    float svals[4];
    #pragma unroll
    for (int nqs = 0; nqs < 4; ++nqs)
        svals[nqs] = spbuf2[0][16 * nqs + l15] + spbuf2[1][16 * nqs + l15]
                   + spbuf2[2][16 * nqs + l15] + spbuf2[3][16 * nqs + l15];

    // O = W*Z + b*svals
    float* ob = out + (size_t)b * CC * NN;
    floatx4 oa[2][4];
    #pragma unroll
    for (int ci = 0; ci < 2; ++ci) {
        int ct = wv + 8 * ci;
        floatx4 bv = *(const floatx4*)(bias + 16 * ct + 4 * q);
        #pragma unroll
        for (int nqs = 0; nqs < 4; ++nqs)
            #pragma unroll
            for (int i = 0; i < 4; ++i) oa[ci][nqs][i] = bv[i] * svals[nqs];
    }
    #pragma unroll
    for (int kk = 0; kk < 8; ++kk) {
        short8 wf0 = *(const short8*)(wF + (size_t)(wv * 8 + kk) * 512 + lane * 8);
        short8 wf1 = *(const short8*)(wF + (size_t)((wv + 8) * 8 + kk) * 512 + lane * 8);
        #pragma unroll
        for (int nqs = 0; nqs < 4; ++nqs) {
            short8 zf = *(const short8*)(&zbuf[(16 * nqs + l15) * 264 + 32 * kk + 8 * q]);
            oa[0][nqs] = mfma16(wf0, zf, oa[0][nqs]);
            oa[1][nqs] = mfma16(wf1, zf, oa[1][nqs]);
        }
    }
    #pragma unroll
    for (int ci = 0; ci < 2; ++ci) {
        int ct = wv + 8 * ci;
        #pragma unroll
        for (int nqs = 0; nqs < 4; ++nqs)
            #pragma unroll
            for (int i = 0; i < 4; ++i)
                ob[(size_t)(16 * ct + 4 * q + i) * NN + n0 + 16 * nqs + l15] = oa[ci][nqs][i];
    }
}

// ---------------------------------------------------------------------------
extern "C" void kernel_launch(void* const* d_in, const int* in_sizes, int n_in,
                              void* d_out, int out_size, void* d_ws, size_t ws_size,
                              hipStream_t stream) {
    const float* x    = (const float*)d_in[0];   // [4,256,64,64]
    const float* Wm   = (const float*)d_in[1];   // [256,256]
    const float* bias = (const float*)d_in[2];   // [256]
    float* out = (float*)d_out;

    // ws: psum 256KB | invn 64KB | xB 8MB | xG 8MB | wF 128KB  (~16.8MB)
    char* ws = (char*)d_ws;
    float* psum         = (float*)ws;
    float* invn         = (float*)(ws + 262144);
    unsigned short* xB  = (unsigned short*)(ws + 262144 + 65536);
    unsigned short* xG  = (unsigned short*)(ws + 262144 + 65536 + 8388608);
    unsigned short* wF  = (unsigned short*)(ws + 262144 + 65536 + 2 * 8388608);

    k_trans   <<<1024, 256, 0, stream>>>(x, xB, xG, psum);
    k_invwcast<<<96,   256, 0, stream>>>(psum, invn, Wm, wF);
    k_fused   <<<256,  512, 0, stream>>>(xB, xG, wF, bias, invn, out);
}

// Round 8
// 165.343 us; speedup vs baseline: 1.2189x; 1.2189x over previous
//
#include <hip/hip_runtime.h>
#include <stdint.h>

#define CC 256
#define NN 4096   // H*W = 64*64

typedef __attribute__((ext_vector_type(8))) short short8;
typedef __attribute__((ext_vector_type(4))) float floatx4;
typedef __attribute__((ext_vector_type(4))) unsigned int uint4v;

__device__ __forceinline__ unsigned short f2bf(float f) {
    unsigned int u = __builtin_bit_cast(unsigned int, f);
    u = (u + 0x7FFFu + ((u >> 16) & 1u)) >> 16;   // RNE
    return (unsigned short)u;
}

__device__ __forceinline__ floatx4 mfma16(short8 a, short8 b, floatx4 c) {
    return __builtin_amdgcn_mfma_f32_16x16x32_bf16(a, b, c, 0, 0, 0);
}

// ---------------------------------------------------------------------------
// Fragment layouts (16x16x32 bf16; A-frag == B-frag lane map:
//   element(row = 16*tile + (lane&15), k = 32*kk + (lane>>4)*8 + j)):
// xB[b][nt 256][kk 8][lane][j] : row = n (pixel), k = c   (S A- and B-operands)
// xG[b][mt 64][cct 16][kk2 2][lane][j] : row = c, k = m   (G2 A-operand)
// wF[ct 16][kk 8][lane][j]     : row = out-c, k = in-c    (epilogue A)
// All R6/R7-proven.
// ---------------------------------------------------------------------------

// ---------------------------------------------------------------------------
// k_trans: x -> xB + xG (bf16 fragment-ordered) + partial norms psum.
// (R7 verbatim)
// ---------------------------------------------------------------------------
__global__ __launch_bounds__(256) void k_trans(const float* __restrict__ x,
                                               unsigned short* __restrict__ xB,
                                               unsigned short* __restrict__ xG,
                                               float* __restrict__ psum) {
    int blk = blockIdx.x;
    int b  = blk >> 8;
    int cc = (blk >> 6) & 3;
    int nc = blk & 63;
    int c0 = cc << 6, n0 = nc << 6;
    __shared__ float tile[64][65];     // [c-local][n-local], +1 pad
    __shared__ float red[4][64];
    int t = threadIdx.x;
    {
        int c   = t >> 2;
        int nn4 = (t & 3) << 4;
        const float* src = x + (size_t)(b * CC + c0 + c) * NN + n0 + nn4;
        #pragma unroll
        for (int j = 0; j < 16; j += 4) {
            floatx4 v = *(const floatx4*)(src + j);
            tile[c][nn4 + j + 0] = v[0];
            tile[c][nn4 + j + 1] = v[1];
            tile[c][nn4 + j + 2] = v[2];
            tile[c][nn4 + j + 3] = v[3];
        }
    }
    __syncthreads();
    int g = t >> 6, lane = t & 63, l15 = lane & 15, q = lane >> 4;
    #pragma unroll
    for (int kkl = 0; kkl < 2; ++kkl) {
        unsigned int w[4];
        #pragma unroll
        for (int j = 0; j < 4; ++j) {
            unsigned int lo = f2bf(tile[32 * kkl + 8 * q + 2 * j][16 * g + l15]);
            unsigned int hi = f2bf(tile[32 * kkl + 8 * q + 2 * j + 1][16 * g + l15]);
            w[j] = lo | (hi << 16);
        }
        uint4v p = {w[0], w[1], w[2], w[3]};
        *(uint4v*)(xB + ((size_t)(b * 256 + (n0 >> 4) + g) * 8 + (c0 >> 5) + kkl) * 512
                   + lane * 8) = p;
    }
    #pragma unroll
    for (int kk2 = 0; kk2 < 2; ++kk2) {
        unsigned int w[4];
        #pragma unroll
        for (int j = 0; j < 4; ++j) {
            unsigned int lo = f2bf(tile[16 * g + l15][32 * kk2 + 8 * q + 2 * j]);
            unsigned int hi = f2bf(tile[16 * g + l15][32 * kk2 + 8 * q + 2 * j + 1]);
            w[j] = lo | (hi << 16);
        }
        uint4v p = {w[0], w[1], w[2], w[3]};
        *(uint4v*)(xG + (size_t)(b * 64 + nc) * 16 * 1024
                   + ((size_t)((c0 >> 4) + g)) * 1024 + kk2 * 512 + lane * 8) = p;
    }
    {
        int n  = t & 63;
        int cq = t >> 6;
        float ss = 0.f;
        #pragma unroll
        for (int i = 0; i < 16; ++i) {
            float v = tile[cq * 16 + i][n];
            ss = fmaf(v, v, ss);
        }
        red[cq][n] = ss;
    }
    __syncthreads();
    if (t < 64) {
        float s = red[0][t] + red[1][t] + red[2][t] + red[3][t];
        psum[((size_t)(b * 64 + nc) * 64 + t) * 4 + cc] = s;
    }
}

// ---------------------------------------------------------------------------
// k_invwcast (R7 verbatim)
// ---------------------------------------------------------------------------
__global__ __launch_bounds__(256) void k_invwcast(const float* __restrict__ psum,
                                                  float* __restrict__ invn,
                                                  const float* __restrict__ Wm,
                                                  unsigned short* __restrict__ wF) {
    int bid = blockIdx.x;
    int t = threadIdx.x;
    if (bid < 64) {
        int i = bid * 256 + t;
        floatx4 p = *(const floatx4*)(psum + (size_t)i * 4);
        float ss = (p[0] + p[1]) + (p[2] + p[3]);
        invn[i] = 1.f / fmaxf(sqrtf(ss), 1e-8f);
    } else {
        int idx = (bid - 64) * 256 + t;          // 0..8191
        int f = idx >> 6, lane = idx & 63;
        int ct = f >> 3, kk = f & 7;
        int l15 = lane & 15, q = lane >> 4;
        const float* src = Wm + (size_t)(16 * ct + l15) * CC + 32 * kk + 8 * q;
        floatx4 a = *(const floatx4*)src;
        floatx4 c = *(const floatx4*)(src + 4);
        unsigned int w0 = f2bf(a[0]) | ((unsigned int)f2bf(a[1]) << 16);
        unsigned int w1 = f2bf(a[2]) | ((unsigned int)f2bf(a[3]) << 16);
        unsigned int w2 = f2bf(c[0]) | ((unsigned int)f2bf(c[1]) << 16);
        unsigned int w3 = f2bf(c[2]) | ((unsigned int)f2bf(c[3]) << 16);
        uint4v p = {w0, w1, w2, w3};
        *(uint4v*)(wF + (size_t)f * 512 + lane * 8) = p;
    }
}

// ---------------------------------------------------------------------------
// k_fused v7: R7 + one-step-ahead register double-buffer for bq.
// Macro-expanded 2x-unrolled loop (no lambdas, no runtime array indexing).
// launch_bounds(512,1): grid 256 = 1 block/CU anyway; avoid spill cap.
// ---------------------------------------------------------------------------
#define FUSED_STEP(IT, BQC, BQN, PB)                                           \
    {                                                                          \
        int m0 = (IT) << 6;                                                    \
        int itn = ((IT) < 63) ? (IT) + 1 : 63;                                 \
        /* issue NEXT step's key B-frags (consumed next step) */               \
        _Pragma("unroll")                                                      \
        for (int kk = 0; kk < 8; ++kk)                                         \
            BQN[kk] = *(const short8*)(xBb                                     \
                + ((size_t)(itn * 4 + ms) * 8 + kk) * 512 + lane * 8);         \
        /* xg A-frags for THIS step (consumed after barrier) */                \
        short8 xg00, xg01, xg10, xg11;                                         \
        xg00 = *(const short8*)(xGb + (size_t)((IT) * 16 + wv) * 1024          \
                                + 0 * 512 + lane * 8);                         \
        xg01 = *(const short8*)(xGb + (size_t)((IT) * 16 + wv) * 1024          \
                                + 1 * 512 + lane * 8);                         \
        xg10 = *(const short8*)(xGb + (size_t)((IT) * 16 + wv + 8) * 1024      \
                                + 0 * 512 + lane * 8);                         \
        xg11 = *(const short8*)(xGb + (size_t)((IT) * 16 + wv + 8) * 1024      \
                                + 1 * 512 + lane * 8);                         \
        float invm = invb[m0 + 16 * ms + l15];                                 \
        /* S = Xq^T Xm using CURRENT (prefetched) bq */                        \
        floatx4 s0a = zero4, s0b = zero4, s1a = zero4, s1b = zero4;            \
        _Pragma("unroll")                                                      \
        for (int kk = 0; kk < 8; kk += 2) {                                    \
            s0a = mfma16(aq[0][kk],     BQC[kk],     s0a);                     \
            s1a = mfma16(aq[1][kk],     BQC[kk],     s1a);                     \
            s0b = mfma16(aq[0][kk + 1], BQC[kk + 1], s0b);                     \
            s1b = mfma16(aq[1][kk + 1], BQC[kk + 1], s1b);                     \
        }                                                                      \
        /* P = relu(S*inv)^2 -> PB (scalar writes) + csum */                   \
        _Pragma("unroll")                                                      \
        for (int s = 0; s < 2; ++s) {                                          \
            floatx4 sv = (s == 0) ? (s0a + s0b) : (s1a + s1b);                 \
            unsigned short* pw = PB + (16 * (2 * np + s)) * 72 + 16 * ms + l15;\
            _Pragma("unroll")                                                  \
            for (int i = 0; i < 4; ++i) {                                      \
                float v = sv[i] * (invq[s][i] * invm);                         \
                v = fmaxf(v, 0.f);                                             \
                v = v * v;                                                     \
                csum[s][i] += v;                                               \
                pw[(q * 4 + i) * 72] = f2bf(v);                                \
            }                                                                  \
        }                                                                      \
        asm volatile("s_waitcnt lgkmcnt(0)\n\ts_barrier" ::: "memory");        \
        /* Z[c][nq] += Xg * P */                                               \
        _Pragma("unroll")                                                      \
        for (int nqs = 0; nqs < 4; ++nqs) {                                    \
            short8 p0 = *(const short8*)(PB + (16 * nqs + l15) * 72 + q * 8);  \
            short8 p1 = *(const short8*)(PB + (16 * nqs + l15) * 72 + 32 + q * 8); \
            Zacc[0][nqs] = mfma16(xg00, p0, Zacc[0][nqs]);                     \
            Zacc[1][nqs] = mfma16(xg10, p0, Zacc[1][nqs]);                     \
            Zacc[0][nqs] = mfma16(xg01, p1, Zacc[0][nqs]);                     \
            Zacc[1][nqs] = mfma16(xg11, p1, Zacc[1][nqs]);                     \
        }                                                                      \
    }

__global__ __launch_bounds__(512, 1) void k_fused(
        const unsigned short* __restrict__ xB,    // S frags
        const unsigned short* __restrict__ xG,    // G2 A frags
        const unsigned short* __restrict__ wF,    // W A-frags
        const float* __restrict__ bias,
        const float* __restrict__ invn,           // [B][N]
        float* __restrict__ out) {                // [B][C][N] f32
    int blk = blockIdx.x;            // b*64 + qtile
    int b  = blk >> 6;
    int n0 = (blk & 63) << 6;
    int t  = threadIdx.x;
    int wv = t >> 6, lane = t & 63;
    int l15 = lane & 15, q = lane >> 4;
    int ms = wv & 3;
    int np = wv >> 2;                // nq pair {2np, 2np+1}

    __shared__ unsigned short pbuf[2][64 * 72];   // [parity][nq row][72 m]
    __shared__ unsigned short zbuf[64 * 264];     // dedicated
    __shared__ float spbuf2[4][64];               // colsum partials [ms][nq]

    const unsigned short* xBb = xB + (size_t)b * 256 * 8 * 512;
    const unsigned short* xGb = xG + (size_t)b * 64 * 16 * 1024;
    const float* invb = invn + b * NN;

    // persistent Xq A-frags from xB (coalesced)
    short8 aq[2][8];
    #pragma unroll
    for (int s = 0; s < 2; ++s)
        #pragma unroll
        for (int kk = 0; kk < 8; ++kk)
            aq[s][kk] = *(const short8*)(xBb
                + ((size_t)((n0 >> 4) + 2 * np + s) * 8 + kk) * 512 + lane * 8);
    float invq[2][4];
    #pragma unroll
    for (int s = 0; s < 2; ++s)
        #pragma unroll
        for (int i = 0; i < 4; ++i)
            invq[s][i] = invb[n0 + 16 * (2 * np + s) + q * 4 + i];

    floatx4 zero4 = {0.f, 0.f, 0.f, 0.f};
    floatx4 Zacc[2][4];              // [ci: cct=wv+8ci][nqs]
    #pragma unroll
    for (int ci = 0; ci < 2; ++ci)
        #pragma unroll
        for (int nqs = 0; nqs < 4; ++nqs) Zacc[ci][nqs] = zero4;
    float csum[2][4];
    #pragma unroll
    for (int s = 0; s < 2; ++s)
        #pragma unroll
        for (int i = 0; i < 4; ++i) csum[s][i] = 0.f;

    // prologue: key tile 0 into bqA
    short8 bqA[8], bqB[8];
    #pragma unroll
    for (int kk = 0; kk < 8; ++kk)
        bqA[kk] = *(const short8*)(xBb + ((size_t)(0 * 4 + ms) * 8 + kk) * 512 + lane * 8);

    for (int it2 = 0; it2 < 32; ++it2) {
        int itE = 2 * it2;
        FUSED_STEP(itE,     bqA, bqB, (pbuf[0]));
        int itO = 2 * it2 + 1;
        FUSED_STEP(itO,     bqB, bqA, (pbuf[1]));
    }

    // ---- colsum reduce over l15 (16-lane groups; pure f32) ----
    #pragma unroll
    for (int mask = 1; mask < 16; mask <<= 1)
        #pragma unroll
        for (int s = 0; s < 2; ++s)
            #pragma unroll
            for (int i = 0; i < 4; ++i)
                csum[s][i] += __shfl_xor(csum[s][i], mask, 64);

    __syncthreads();
    // Z -> zbuf (scalar stores, dedicated LDS)
    #pragma unroll
    for (int ci = 0; ci < 2; ++ci) {
        int cct = wv + 8 * ci;
        #pragma unroll
        for (int nqs = 0; nqs < 4; ++nqs)
            #pragma unroll
            for (int i = 0; i < 4; ++i)
                zbuf[(16 * nqs + l15) * 264 + 16 * cct + 4 * q + i] = f2bf(Zacc[ci][nqs][i]);
    }
    if (l15 == 0) {
        #pragma unroll
        for (int s = 0; s < 2; ++s)
            #pragma unroll
            for (int i = 0; i < 4; ++i)
                spbuf2[ms][16 * (2 * np + s) + 4 * q + i] = csum[s][i];
    }
    __syncthreads();

    float svals[4];
    #pragma unroll
    for (int nqs = 0; nqs < 4; ++nqs)
        svals[nqs] = spbuf2[0][16 * nqs + l15] + spbuf2[1][16 * nqs + l15]
                   + spbuf2[2][16 * nqs + l15] + spbuf2[3][16 * nqs + l15];

    // O = W*Z + b*svals
    float* ob = out + (size_t)b * CC * NN;
    floatx4 oa[2][4];
    #pragma unroll
    for (int ci = 0; ci < 2; ++ci) {
        int ct = wv + 8 * ci;
        floatx4 bv = *(const floatx4*)(bias + 16 * ct + 4 * q);
        #pragma unroll
        for (int nqs = 0; nqs < 4; ++nqs)
            #pragma unroll
            for (int i = 0; i < 4; ++i) oa[ci][nqs][i] = bv[i] * svals[nqs];
    }
    #pragma unroll
    for (int kk = 0; kk < 8; ++kk) {
        short8 wf0 = *(const short8*)(wF + (size_t)(wv * 8 + kk) * 512 + lane * 8);
        short8 wf1 = *(const short8*)(wF + (size_t)((wv + 8) * 8 + kk) * 512 + lane * 8);
        #pragma unroll
        for (int nqs = 0; nqs < 4; ++nqs) {
            short8 zf = *(const short8*)(&zbuf[(16 * nqs + l15) * 264 + 32 * kk + 8 * q]);
            oa[0][nqs] = mfma16(wf0, zf, oa[0][nqs]);
            oa[1][nqs] = mfma16(wf1, zf, oa[1][nqs]);
        }
    }
    #pragma unroll
    for (int ci = 0; ci < 2; ++ci) {
        int ct = wv + 8 * ci;
        #pragma unroll
        for (int nqs = 0; nqs < 4; ++nqs)
            #pragma unroll
            for (int i = 0; i < 4; ++i)
                ob[(size_t)(16 * ct + 4 * q + i) * NN + n0 + 16 * nqs + l15] = oa[ci][nqs][i];
    }
}

// ---------------------------------------------------------------------------
extern "C" void kernel_launch(void* const* d_in, const int* in_sizes, int n_in,
                              void* d_out, int out_size, void* d_ws, size_t ws_size,
                              hipStream_t stream) {
    const float* x    = (const float*)d_in[0];   // [4,256,64,64]
    const float* Wm   = (const float*)d_in[1];   // [256,256]
    const float* bias = (const float*)d_in[2];   // [256]
    float* out = (float*)d_out;

    // ws: psum 256KB | invn 64KB | xB 8MB | xG 8MB | wF 128KB  (~16.8MB)
    char* ws = (char*)d_ws;
    float* psum         = (float*)ws;
    float* invn         = (float*)(ws + 262144);
    unsigned short* xB  = (unsigned short*)(ws + 262144 + 65536);
    unsigned short* xG  = (unsigned short*)(ws + 262144 + 65536 + 8388608);
    unsigned short* wF  = (unsigned short*)(ws + 262144 + 65536 + 2 * 8388608);

    k_trans   <<<1024, 256, 0, stream>>>(x, xB, xG, psum);
    k_invwcast<<<96,   256, 0, stream>>>(psum, invn, Wm, wF);
    k_fused   <<<256,  512, 0, stream>>>(xB, xG, wF, bias, invn, out);
}